// Round 10
// baseline (1417.182 us; speedup 1.0000x reference)
//
#include <hip/hip_runtime.h>
#include <hip/hip_bf16.h>
#include <cstdint>
#include <cstddef>

#define B 64
#define T 512
#define EMBED 128
#define H 128
#define G4 512          // 4*H
#define HOUT 256        // 2*H (bilstm concat)
#define NUM_CLASSES 10
#define BT (B * T)      // 32768

typedef float v2f __attribute__((ext_vector_type(2)));
typedef float v4f __attribute__((ext_vector_type(4)));

// ---------------------------------------------------------------------------
// 1) GEMM: C(M,G4) = A(M,K) @ W(K,G4) + bias(G4)
//    BM=128, BN=64, BK=16, 256 threads, 8x4 micro-tile.
//    If xrow != nullptr, A-row m is A[xrow[m], :] (embedding fusion).
// ---------------------------------------------------------------------------
#define BM 128
#define BN 64
#define BK 16

__global__ __launch_bounds__(256) void gemm_bias_kernel(
    const float* __restrict__ A, const int* __restrict__ xrow,
    const float* __restrict__ W, const float* __restrict__ bias,
    float* __restrict__ C, int K)
{
    __shared__ __align__(16) float As[BK][BM + 4];  // transposed: As[k][m]
    __shared__ __align__(16) float Ws[BK][BN + 4];  // Ws[k][n]

    int tid = threadIdx.x;
    int tx = tid & 15;    // N direction, 16 x 4 = 64
    int ty = tid >> 4;    // M direction, 16 x 8 = 128
    int m0 = blockIdx.y * BM;
    int n0 = blockIdx.x * BN;

    // A-row pointers for this thread's two staging rows (fixed across k-tiles)
    int ra = tid >> 2;        // 0..63
    int cq = tid & 3;         // float4 slot in k
    const float* arow0;
    const float* arow1;
    if (xrow) {
        arow0 = A + (size_t)xrow[m0 + ra] * K;
        arow1 = A + (size_t)xrow[m0 + ra + 64] * K;
    } else {
        arow0 = A + (size_t)(m0 + ra) * K;
        arow1 = A + (size_t)(m0 + ra + 64) * K;
    }

    float acc[8][4];
#pragma unroll
    for (int i = 0; i < 8; i++)
#pragma unroll
        for (int j = 0; j < 4; j++) acc[i][j] = 0.f;

    for (int k0 = 0; k0 < K; k0 += BK) {
        // A tile: 128 rows x 16 k (store transposed)
        {
            float4 a = *(const float4*)&arow0[k0 + cq * 4];
            As[cq * 4 + 0][ra] = a.x;
            As[cq * 4 + 1][ra] = a.y;
            As[cq * 4 + 2][ra] = a.z;
            As[cq * 4 + 3][ra] = a.w;
            float4 b = *(const float4*)&arow1[k0 + cq * 4];
            As[cq * 4 + 0][ra + 64] = b.x;
            As[cq * 4 + 1][ra + 64] = b.y;
            As[cq * 4 + 2][ra + 64] = b.z;
            As[cq * 4 + 3][ra + 64] = b.w;
        }
        // W tile: 16 k x 64 n = 256 float4, 1 per thread
        {
            int rw = tid >> 4;                // 0..15
            int cw = tid & 15;
            float4 wv = *(const float4*)&W[(size_t)(k0 + rw) * G4 + n0 + cw * 4];
            *(float4*)&Ws[rw][cw * 4] = wv;
        }
        __syncthreads();

#pragma unroll
        for (int k = 0; k < BK; k++) {
            float4 a0 = *(const float4*)&As[k][ty * 8];
            float4 a1 = *(const float4*)&As[k][ty * 8 + 4];
            float4 w0 = *(const float4*)&Ws[k][tx * 4];
            float av[8] = {a0.x, a0.y, a0.z, a0.w, a1.x, a1.y, a1.z, a1.w};
            float wv[4] = {w0.x, w0.y, w0.z, w0.w};
#pragma unroll
            for (int i = 0; i < 8; i++)
#pragma unroll
                for (int j = 0; j < 4; j++)
                    acc[i][j] = fmaf(av[i], wv[j], acc[i][j]);
        }
        __syncthreads();
    }

    float4 bv = *(const float4*)&bias[n0 + tx * 4];
#pragma unroll
    for (int i = 0; i < 8; i++) {
        int m = m0 + ty * 8 + i;
        float4 o;
        o.x = acc[i][0] + bv.x;
        o.y = acc[i][1] + bv.y;
        o.z = acc[i][2] + bv.z;
        o.w = acc[i][3] + bv.w;
        *(float4*)&C[(size_t)m * G4 + n0 + tx * 4] = o;
    }
}

// ---------------------------------------------------------------------------
// 2) LSTM scan v9b: one WG (256 threads, 4 waves) per (batch, direction).
//    tid = qp*4 + kq: thread owns TWO adjacent columns q0=2qp, q0+1
//    over k in [32kq, 32kq+32) -> the 128-B h-slice read from LDS is
//    REUSED for both columns: LDS traffic/step halves vs v6 (the measured
//    binding floor: 64 -> 32 ds_read_b128/CU/step).
//    Pair tags: A = column q0, Z = column q0+1 (NOT 'B': #define B 64
//    would macro-expand inside DECLC before pasting -- r9 compile bug).
//    - 128 weight v2f (256 VGPRs) named + asm-pinned; waves_per_eu(1,1)
//      gives the full 512-VGPR budget (1 WG/CU anyway -> TLP irrelevant).
//    - 256 MACs/thread via 128 v_pk_fma_f32 (packed along k).
//    - kq-quad combine: 2 DPP quad_perm butterfly levels (8 accs).
//    - h/hout written as paired b64 by kq==0 lanes (conflict-free).
//    - one LDS-only-drain barrier per step, double-buffered h. All f32.
// ---------------------------------------------------------------------------
__device__ __forceinline__ float fast_sig(float x) {
    // 1/(1+e^-x); inf-safe: e=inf -> rcp(inf)=0
    float e = __expf(-x);
    return __builtin_amdgcn_rcpf(1.f + e);
}

template <int CTRL>
__device__ __forceinline__ float dpp_add(float x) {
    int y = __builtin_amdgcn_mov_dpp(__float_as_int(x), CTRL, 0xF, 0xF, true);
    return x + __int_as_float(y);
}

__device__ __forceinline__ void wg_barrier_lds() {
    asm volatile("s_waitcnt lgkmcnt(0)" ::: "memory");
    __builtin_amdgcn_s_barrier();
}

#define PKFMA(acc, h2, w2) \
    asm("v_pk_fma_f32 %0, %1, %2, %0" : "+v"(acc) : "v"(h2), "v"(w2))

__global__ __launch_bounds__(256) __attribute__((amdgpu_waves_per_eu(1, 1)))
void lstm_scan_kernel(
    const float* __restrict__ xp0, const float* __restrict__ xp1,
    const float* __restrict__ Wh0, const float* __restrict__ Wh1,
    const int* __restrict__ x, float* __restrict__ hout)
{
    const int b   = blockIdx.x;
    const int dir = blockIdx.y;  // 0 = forward, 1 = reverse
    const float* __restrict__ xp = dir ? xp1 : xp0;
    const float* __restrict__ Wh = dir ? Wh1 : Wh0;

    const int tid = threadIdx.x;
    const int kq  = tid & 3;     // k-slice 0..3 -> k in [32kq, 32kq+32)
    const int qp  = tid >> 2;    // column pair 0..63
    const int q0  = 2 * qp;      // columns q0, q0+1

    // weights: pair p of gate c, column col = (Wh[32kq+2p][col], Wh[32kq+2p+1][col])
    const float* wpb = Wh + (size_t)(kq * 32) * G4;
#define LDP(P, c, p, col) v2f w##P##c##_##p = { wpb[(2 * p) * G4 + (col)], \
                                                wpb[(2 * p + 1) * G4 + (col)] };
#define DECLC(P, c, col) \
    LDP(P, c, 0, col)  LDP(P, c, 1, col)  LDP(P, c, 2, col)  LDP(P, c, 3, col)  \
    LDP(P, c, 4, col)  LDP(P, c, 5, col)  LDP(P, c, 6, col)  LDP(P, c, 7, col)  \
    LDP(P, c, 8, col)  LDP(P, c, 9, col)  LDP(P, c, 10, col) LDP(P, c, 11, col) \
    LDP(P, c, 12, col) LDP(P, c, 13, col) LDP(P, c, 14, col) LDP(P, c, 15, col)
    DECLC(A, 0, 0 * H + q0) DECLC(A, 1, 1 * H + q0)
    DECLC(A, 2, 2 * H + q0) DECLC(A, 3, 3 * H + q0)
    DECLC(Z, 0, 0 * H + q0 + 1) DECLC(Z, 1, 1 * H + q0 + 1)
    DECLC(Z, 2, 2 * H + q0 + 1) DECLC(Z, 3, 3 * H + q0 + 1)
#undef DECLC
#undef LDP
#define PIN4(a, b_, c_, d_) asm volatile("" : "+v"(a), "+v"(b_), "+v"(c_), "+v"(d_))
#define PINC(P, c) \
    PIN4(w##P##c##_0,  w##P##c##_1,  w##P##c##_2,  w##P##c##_3);  \
    PIN4(w##P##c##_4,  w##P##c##_5,  w##P##c##_6,  w##P##c##_7);  \
    PIN4(w##P##c##_8,  w##P##c##_9,  w##P##c##_10, w##P##c##_11); \
    PIN4(w##P##c##_12, w##P##c##_13, w##P##c##_14, w##P##c##_15)
    PINC(A, 0); PINC(A, 1); PINC(A, 2); PINC(A, 3);
    PINC(Z, 0); PINC(Z, 1); PINC(Z, 2); PINC(Z, 3);
#undef PINC
#undef PIN4

    // h: [buf][block kq][32 data + 4 skew]; block bases at banks
    // {0,4,8,12} (buf 0) / {16,20,24,28} (buf 1) -> wave's 4 distinct
    // b128 addresses are bank-disjoint at every kk; 16-lane broadcast.
    __shared__ __align__(16) float h_sh[2][4][36];
    __shared__ unsigned char mask_sh[T];

    if (tid < H) h_sh[0][tid >> 5][tid & 31] = 0.f;
    mask_sh[tid]       = (x[(size_t)b * T + tid] != 0) ? 1 : 0;
    mask_sh[tid + 256] = (x[(size_t)b * T + tid + 256] != 0) ? 1 : 0;
    float cA = 0.f, hA = 0.f, cZ = 0.f, hZ = 0.f;
    __syncthreads();

    const int t0 = dir ? T - 1 : 0;
    const ptrdiff_t dstep = dir ? -(ptrdiff_t)G4 : (ptrdiff_t)G4;
    const ptrdiff_t hstep = dir ? -(ptrdiff_t)HOUT : (ptrdiff_t)HOUT;
    const float* xptr = xp + ((size_t)b * T + t0) * G4 + kq * H + q0;
    float*       hptr = hout + ((size_t)b * T + t0) * HOUT + dir * H + q0;
    v2f xp_cur = *(const v2f*)xptr;

    int cb = 0;
    int t = t0;
    const int tinc = dir ? -1 : 1;

    for (int s = 0; s < T; s++) {
        v2f xin = xp_cur;
        if (s + 1 < T) {           // prefetch next step's xp (pair load)
            xptr += dstep;
            xp_cur = *(const v2f*)xptr;
        }

        // packed partials, 8 accumulators (4 gates x 2 columns)
        v2f aA0 = { (kq == 0) ? xin.x : 0.f, 0.f };
        v2f aA1 = { (kq == 1) ? xin.x : 0.f, 0.f };
        v2f aA2 = { (kq == 2) ? xin.x : 0.f, 0.f };
        v2f aA3 = { (kq == 3) ? xin.x : 0.f, 0.f };
        v2f aZ0 = { (kq == 0) ? xin.y : 0.f, 0.f };
        v2f aZ1 = { (kq == 1) ? xin.y : 0.f, 0.f };
        v2f aZ2 = { (kq == 2) ? xin.y : 0.f, 0.f };
        v2f aZ3 = { (kq == 3) ? xin.y : 0.f, 0.f };

        const v4f* hp = (const v4f*)&h_sh[cb][kq][0];
#define BLK(kk, pA, pB) {                                                     \
        v4f hv = hp[kk];                                                      \
        v2f h01 = __builtin_shufflevector(hv, hv, 0, 1);                      \
        v2f h23 = __builtin_shufflevector(hv, hv, 2, 3);                      \
        PKFMA(aA0, h01, wA0_##pA); PKFMA(aA0, h23, wA0_##pB);                 \
        PKFMA(aA1, h01, wA1_##pA); PKFMA(aA1, h23, wA1_##pB);                 \
        PKFMA(aA2, h01, wA2_##pA); PKFMA(aA2, h23, wA2_##pB);                 \
        PKFMA(aA3, h01, wA3_##pA); PKFMA(aA3, h23, wA3_##pB);                 \
        PKFMA(aZ0, h01, wZ0_##pA); PKFMA(aZ0, h23, wZ0_##pB);                 \
        PKFMA(aZ1, h01, wZ1_##pA); PKFMA(aZ1, h23, wZ1_##pB);                 \
        PKFMA(aZ2, h01, wZ2_##pA); PKFMA(aZ2, h23, wZ2_##pB);                 \
        PKFMA(aZ3, h01, wZ3_##pA); PKFMA(aZ3, h23, wZ3_##pB); }
        BLK(0, 0, 1)   BLK(1, 2, 3)   BLK(2, 4, 5)   BLK(3, 6, 7)
        BLK(4, 8, 9)   BLK(5, 10, 11) BLK(6, 12, 13) BLK(7, 14, 15)
#undef BLK

        float zA0 = aA0.x + aA0.y, zA1 = aA1.x + aA1.y;
        float zA2 = aA2.x + aA2.y, zA3 = aA3.x + aA3.y;
        float zZ0 = aZ0.x + aZ0.y, zZ1 = aZ1.x + aZ1.y;
        float zZ2 = aZ2.x + aZ2.y, zZ3 = aZ3.x + aZ3.y;

        // butterfly over the 4 kq-lanes (quad_perm DPP): xor1, xor2
        zA0 = dpp_add<0xB1>(zA0); zA1 = dpp_add<0xB1>(zA1);
        zA2 = dpp_add<0xB1>(zA2); zA3 = dpp_add<0xB1>(zA3);
        zZ0 = dpp_add<0xB1>(zZ0); zZ1 = dpp_add<0xB1>(zZ1);
        zZ2 = dpp_add<0xB1>(zZ2); zZ3 = dpp_add<0xB1>(zZ3);
        zA0 = dpp_add<0x4E>(zA0); zA1 = dpp_add<0x4E>(zA1);
        zA2 = dpp_add<0x4E>(zA2); zA3 = dpp_add<0x4E>(zA3);
        zZ0 = dpp_add<0x4E>(zZ0); zZ1 = dpp_add<0x4E>(zZ1);
        zZ2 = dpp_add<0x4E>(zZ2); zZ3 = dpp_add<0x4E>(zZ3);

        // gates for both columns (lane-local, redundant across the quad)
        float igA = fast_sig(zA0);
        float fgA = fast_sig(zA1);
        float ggA = 2.f * fast_sig(zA2 + zA2) - 1.f;   // tanh
        float ogA = fast_sig(zA3);
        float cnA = fmaf(fgA, cA, igA * ggA);
        float thA = 2.f * fast_sig(cnA + cnA) - 1.f;   // tanh
        float hnA = ogA * thA;

        float igZ = fast_sig(zZ0);
        float fgZ = fast_sig(zZ1);
        float ggZ = 2.f * fast_sig(zZ2 + zZ2) - 1.f;   // tanh
        float ogZ = fast_sig(zZ3);
        float cnZ = fmaf(fgZ, cZ, igZ * ggZ);
        float thZ = 2.f * fast_sig(cnZ + cnZ) - 1.f;   // tanh
        float hnZ = ogZ * thZ;

        bool msk = mask_sh[t] != 0;
        cA = msk ? cnA : cA;  hA = msk ? hnA : hA;
        cZ = msk ? cnZ : cZ;  hZ = msk ? hnZ : hZ;

        if (kq == 0) {  // one lane per column-pair writes both (b64)
            v2f hw = { hA, hZ };
            *(v2f*)&h_sh[cb ^ 1][q0 >> 5][q0 & 31] = hw;
            *(v2f*)hptr = hw;
        }
        hptr += hstep;
        wg_barrier_lds();          // LDS-only drain: vmcnt stays in flight
        cb ^= 1;
        t += tinc;
    }
}

// ---------------------------------------------------------------------------
// 3) pooling: per (b,t) max & mean over 256 channels -> feat (B, 2T)
// ---------------------------------------------------------------------------
__global__ __launch_bounds__(256) void pool_kernel(
    const float* __restrict__ Hin, float* __restrict__ feat)
{
    int wave = threadIdx.x >> 6;
    int lane = threadIdx.x & 63;
    int bt = blockIdx.x * 4 + wave;
    float4 v = *(const float4*)&Hin[(size_t)bt * HOUT + lane * 4];
    float mx = fmaxf(fmaxf(v.x, v.y), fmaxf(v.z, v.w));
    float sm = (v.x + v.y) + (v.z + v.w);
#pragma unroll
    for (int off = 32; off > 0; off >>= 1) {
        mx = fmaxf(mx, __shfl_down(mx, off));
        sm += __shfl_down(sm, off);
    }
    if (lane == 0) {
        int b = bt >> 9;        // /T
        int t = bt & (T - 1);
        feat[(size_t)b * (2 * T) + t]     = mx;
        feat[(size_t)b * (2 * T) + T + t] = sm * (1.f / 256.f);
    }
}

// ---------------------------------------------------------------------------
// 4) FC: out(B,10) = relu(feat(B,1024) @ fcW(1024,10) + fcb)
// ---------------------------------------------------------------------------
__global__ __launch_bounds__(128) void fc_kernel(
    const float* __restrict__ feat, const float* __restrict__ fcW,
    const float* __restrict__ fcb, float* __restrict__ out)
{
    __shared__ float red[2][NUM_CLASSES];
    int b = blockIdx.x, tid = threadIdx.x;
    float acc[NUM_CLASSES];
#pragma unroll
    for (int c = 0; c < NUM_CLASSES; c++) acc[c] = 0.f;
#pragma unroll
    for (int it = 0; it < 8; it++) {
        int k = tid + it * 128;
        float fv = feat[(size_t)b * 1024 + k];
#pragma unroll
        for (int c = 0; c < NUM_CLASSES; c++)
            acc[c] = fmaf(fv, fcW[(size_t)k * NUM_CLASSES + c], acc[c]);
    }
#pragma unroll
    for (int c = 0; c < NUM_CLASSES; c++) {
        float v = acc[c];
        for (int off = 32; off > 0; off >>= 1) v += __shfl_down(v, off);
        if ((tid & 63) == 0) red[tid >> 6][c] = v;
    }
    __syncthreads();
    if (tid < NUM_CLASSES) {
        float v = red[0][tid] + red[1][tid] + fcb[tid];
        out[(size_t)b * NUM_CLASSES + tid] = fmaxf(v, 0.f);
    }
}

// ---------------------------------------------------------------------------
// launch
// ---------------------------------------------------------------------------
extern "C" void kernel_launch(void* const* d_in, const int* in_sizes, int n_in,
                              void* d_out, int out_size, void* d_ws, size_t ws_size,
                              hipStream_t stream)
{
    const int*   x     = (const int*)d_in[0];
    const float* emb   = (const float*)d_in[1];
    const float* Wx_f0 = (const float*)d_in[2];
    const float* Wh_f0 = (const float*)d_in[3];
    const float* b_f0  = (const float*)d_in[4];
    const float* Wx_b0 = (const float*)d_in[5];
    const float* Wh_b0 = (const float*)d_in[6];
    const float* b_b0  = (const float*)d_in[7];
    const float* Wx_f1 = (const float*)d_in[8];
    const float* Wh_f1 = (const float*)d_in[9];
    const float* b_f1  = (const float*)d_in[10];
    const float* Wx_b1 = (const float*)d_in[11];
    const float* Wh_b1 = (const float*)d_in[12];
    const float* b_b1  = (const float*)d_in[13];
    const float* fcW   = (const float*)d_in[14];
    const float* fcb   = (const float*)d_in[15];
    float* out = (float*)d_out;

    char* ws = (char*)d_ws;
    const size_t MB = 1024 * 1024;
    float* H1   = (float*)(ws);                  // 32 MB  (BT x 256)
    float* H0   = (float*)(ws + 32 * MB);        // 32 MB  (BT x 256)
    float* xpF  = (float*)(ws + 64 * MB);        // 64 MB  (BT x 512)
    float* xpB  = (float*)(ws + 128 * MB);       // 64 MB  (BT x 512)
    float* feat = (float*)(ws + 192 * MB);       // 256 KB (B x 1024)

    dim3 ggrid(G4 / BN, BT / BM);  // (8, 256)

    // layer 0 (A-rows gathered from emb on the fly)
    gemm_bias_kernel<<<ggrid, 256, 0, stream>>>(emb, x, Wx_f0, b_f0, xpF, EMBED);
    gemm_bias_kernel<<<ggrid, 256, 0, stream>>>(emb, x, Wx_b0, b_b0, xpB, EMBED);
    lstm_scan_kernel<<<dim3(B, 2), 256, 0, stream>>>(xpF, xpB, Wh_f0, Wh_b0, x, H0);

    // layer 1 (input = H0, K = 256)
    gemm_bias_kernel<<<ggrid, 256, 0, stream>>>(H0, nullptr, Wx_f1, b_f1, xpF, 2 * H);
    gemm_bias_kernel<<<ggrid, 256, 0, stream>>>(H0, nullptr, Wx_b1, b_b1, xpB, 2 * H);
    lstm_scan_kernel<<<dim3(B, 2), 256, 0, stream>>>(xpF, xpB, Wh_f1, Wh_b1, x, H1);

    // pooling + FC
    pool_kernel<<<BT / 4, 256, 0, stream>>>(H1, feat);
    fc_kernel<<<B, 128, 0, stream>>>(feat, fcW, fcb, out);
}

// Round 11
// 872.802 us; speedup vs baseline: 1.6237x; 1.6237x over previous
//
#include <hip/hip_runtime.h>
#include <hip/hip_bf16.h>
#include <cstdint>
#include <cstddef>

#define B 64
#define T 512
#define EMBED 128
#define H 128
#define G4 512          // 4*H
#define HOUT 256        // 2*H (bilstm concat)
#define NUM_CLASSES 10
#define BT (B * T)      // 32768

typedef float v2f __attribute__((ext_vector_type(2)));
typedef float v4f __attribute__((ext_vector_type(4)));
typedef short v8s __attribute__((ext_vector_type(8)));   // 8 bf16 (4 VGPRs)

// ---------------------------------------------------------------------------
// bf16 split helpers (truncation; hi+lo ~ 2^-17 relative)
// ---------------------------------------------------------------------------
__device__ __forceinline__ unsigned short bf16_hi(float v) {
    return (unsigned short)(__float_as_uint(v) >> 16);
}
__device__ __forceinline__ unsigned short bf16_lo(float v, unsigned short hi) {
    float hf = __uint_as_float((unsigned)hi << 16);
    return (unsigned short)(__float_as_uint(v - hf) >> 16);
}

// ---------------------------------------------------------------------------
// 1a) prep_w2t: w2t[n][j] bf16, n in [0,1024): col n of (n<512 ? Wf : Wb).
//     j in [0,K): hi(W[j][n]); j in [K,2K): lo(W[j][n]).
// ---------------------------------------------------------------------------
__global__ __launch_bounds__(128) void prep_w2t_kernel(
    const float* __restrict__ Wf, const float* __restrict__ Wb,
    unsigned short* __restrict__ w2t, int K)
{
    int n = blockIdx.x;
    const float* src = (n < 512) ? (Wf + n) : (Wb + (n - 512));
    unsigned short* dst = w2t + (size_t)n * (2 * K);
    for (int j = threadIdx.x; j < K; j += 128) {
        float v = src[(size_t)j * G4];
        unsigned short hi = bf16_hi(v);
        dst[j]     = hi;
        dst[K + j] = bf16_lo(v, hi);
    }
}

// ---------------------------------------------------------------------------
// 1b) prep_a2_emb: a2[m][0..128)=hi(emb[x[m]][j]), [128..256)=lo. K=128.
// ---------------------------------------------------------------------------
__global__ __launch_bounds__(128) void prep_a2_emb_kernel(
    const int* __restrict__ x, const float* __restrict__ emb,
    unsigned short* __restrict__ a2)
{
    int m = blockIdx.x;
    int j = threadIdx.x;
    float v = emb[(size_t)x[m] * EMBED + j];
    unsigned short hi = bf16_hi(v);
    a2[(size_t)m * 256 + j]       = hi;
    a2[(size_t)m * 256 + 128 + j] = bf16_lo(v, hi);
}

// ---------------------------------------------------------------------------
// 1c) prep_a2_h: from H0 (BT x 256 f32). a2 row = [hi(256) | lo(256)].
// ---------------------------------------------------------------------------
__global__ __launch_bounds__(256) void prep_a2_h_kernel(
    const float* __restrict__ H0, unsigned short* __restrict__ a2)
{
    int m = blockIdx.x;
    int j = threadIdx.x;
    float v = H0[(size_t)m * 256 + j];
    unsigned short hi = bf16_hi(v);
    a2[(size_t)m * 512 + j]       = hi;
    a2[(size_t)m * 512 + 256 + j] = bf16_lo(v, hi);
}

// ---------------------------------------------------------------------------
// 2) MFMA GEMM: C(M,1024) = A(M,K) @ [Wf|Wb](K,1024) + bias, computed as
//    3-term bf16 split: Ah@Wh + Ah@Wl + Al@Wh (term-indexed k-loop over
//    a2=[Ah|Al], w2t=[Wh|Wl]). Cols [0,512)->xpF, [512,1024)->xpB.
//    BM=BN=128, 256 thr = 4 waves, wave quadrant 64x64 = 4x4 frags of
//    mfma_f32_16x16x32_bf16. LDS tiles [128 rows][40 halfs] (80B stride:
//    frag reads max 4-way bank conflict = 1.58x, acceptable).
//    Fragment maps: A row = lane&15, k = (lane>>4)*8+i (LDS k-contiguous);
//    W col = lane&15 (w2t stores W transposed), same k map -> any k-perm
//    error cancels between A and B. C/D: col=lane&15, row=(lane>>4)*4+reg
//    (HW-verified mapping).
// ---------------------------------------------------------------------------
__global__ __launch_bounds__(256) void gemm_mfma_kernel(
    const unsigned short* __restrict__ a2, const unsigned short* __restrict__ w2t,
    const float* __restrict__ bF, const float* __restrict__ bB,
    float* __restrict__ xpF, float* __restrict__ xpB, int K)
{
    __shared__ __align__(16) unsigned short As[128 * 40];
    __shared__ __align__(16) unsigned short Ws[128 * 40];

    const int tid  = threadIdx.x;
    const int lane = tid & 63;
    const int wv   = tid >> 6;        // wave 0..3
    const int wr   = wv >> 1;         // row half
    const int wc   = wv & 1;          // col half
    const int n0   = blockIdx.x * 128;
    const int m0   = blockIdx.y * 128;
    const int K2   = 2 * K;

    // staging coords: thread -> (row, 32-byte part)
    const int srow  = tid >> 1;
    const int spart = tid & 1;
    const unsigned short* agp = a2 + (size_t)(m0 + srow) * K2 + spart * 16;
    const unsigned short* wgp = w2t + (size_t)(n0 + srow) * K2 + spart * 16;
    unsigned short* alp = &As[srow * 40 + spart * 16];
    unsigned short* wlp = &Ws[srow * 40 + spart * 16];

    v4f acc[4][4];
#pragma unroll
    for (int i = 0; i < 4; i++)
#pragma unroll
        for (int j = 0; j < 4; j++) acc[i][j] = (v4f){0.f, 0.f, 0.f, 0.f};

    const int ksub = K >> 5;          // k-steps per term
    const int nsteps = 3 * ksub;
    for (int s = 0; s < nsteps; ++s) {
        int t  = s / ksub;
        int kk = s - t * ksub;
        int aoff = ((t == 2) ? K : 0) + kk * 32;
        int woff = ((t == 1) ? K : 0) + kk * 32;

        // stage 128x32 bf16 tiles (each thread: 2x16B per tile)
        {
            v8s a0 = *(const v8s*)(agp + aoff);
            v8s a1 = *(const v8s*)(agp + aoff + 8);
            v8s w0 = *(const v8s*)(wgp + woff);
            v8s w1 = *(const v8s*)(wgp + woff + 8);
            *(v8s*)(alp)     = a0;
            *(v8s*)(alp + 8) = a1;
            *(v8s*)(wlp)     = w0;
            *(v8s*)(wlp + 8) = w1;
        }
        __syncthreads();

        // fragments: 4 A (m-reps) + 4 W (n-reps), then 16 MFMA
        v8s af[4], wf[4];
#pragma unroll
        for (int mr = 0; mr < 4; mr++)
            af[mr] = *(const v8s*)&As[(wr * 64 + mr * 16 + (lane & 15)) * 40 + (lane >> 4) * 8];
#pragma unroll
        for (int nr = 0; nr < 4; nr++)
            wf[nr] = *(const v8s*)&Ws[(wc * 64 + nr * 16 + (lane & 15)) * 40 + (lane >> 4) * 8];
#pragma unroll
        for (int mr = 0; mr < 4; mr++)
#pragma unroll
            for (int nr = 0; nr < 4; nr++)
                acc[mr][nr] = __builtin_amdgcn_mfma_f32_16x16x32_bf16(
                    af[mr], wf[nr], acc[mr][nr], 0, 0, 0);
        __syncthreads();
    }

    // epilogue: D col=lane&15, row=(lane>>4)*4+reg
#pragma unroll
    for (int nr = 0; nr < 4; nr++) {
        int gcol = n0 + wc * 64 + nr * 16 + (lane & 15);
        float bv = (gcol < 512) ? bF[gcol] : bB[gcol - 512];
        float* dst = (gcol < 512) ? (xpF + gcol) : (xpB + gcol - 512);
#pragma unroll
        for (int mr = 0; mr < 4; mr++) {
            int grow = m0 + wr * 64 + mr * 16 + (lane >> 4) * 4;
            v4f fr = acc[mr][nr];
#pragma unroll
            for (int r = 0; r < 4; r++)
                dst[(size_t)(grow + r) * G4] = fr[r] + bv;
        }
    }
}

// ---------------------------------------------------------------------------
// 3) LSTM scan v6 (verbatim round-6 kernel, 353 us known-good):
//    512 thr, tid=q*4+ks, pk_fma, DPP butterfly, LDS-only barrier drain.
// ---------------------------------------------------------------------------
__device__ __forceinline__ float fast_sig(float x) {
    float e = __expf(-x);
    return __builtin_amdgcn_rcpf(1.f + e);
}

template <int CTRL>
__device__ __forceinline__ float dpp_add(float x) {
    int y = __builtin_amdgcn_mov_dpp(__float_as_int(x), CTRL, 0xF, 0xF, true);
    return x + __int_as_float(y);
}

__device__ __forceinline__ void wg_barrier_lds() {
    asm volatile("s_waitcnt lgkmcnt(0)" ::: "memory");
    __builtin_amdgcn_s_barrier();
}

#define PKFMA(acc, h2, w2) \
    asm("v_pk_fma_f32 %0, %1, %2, %0" : "+v"(acc) : "v"(h2), "v"(w2))

__global__ __launch_bounds__(512) __attribute__((amdgpu_waves_per_eu(2, 2)))
void lstm_scan_kernel(
    const float* __restrict__ xp0, const float* __restrict__ xp1,
    const float* __restrict__ Wh0, const float* __restrict__ Wh1,
    const int* __restrict__ x, float* __restrict__ hout)
{
    const int b   = blockIdx.x;
    const int dir = blockIdx.y;
    const float* __restrict__ xp = dir ? xp1 : xp0;
    const float* __restrict__ Wh = dir ? Wh1 : Wh0;

    const int tid = threadIdx.x;
    const int ks  = tid & 3;
    const int q   = tid >> 2;

    const float* wp = Wh + (size_t)(ks * 32) * G4 + q;
#define LDP(c, p) v2f w##c##_##p = { wp[(2 * p) * G4 + c * H], \
                                     wp[(2 * p + 1) * G4 + c * H] }
#define DECLC(c) \
    LDP(c, 0);  LDP(c, 1);  LDP(c, 2);  LDP(c, 3);  \
    LDP(c, 4);  LDP(c, 5);  LDP(c, 6);  LDP(c, 7);  \
    LDP(c, 8);  LDP(c, 9);  LDP(c, 10); LDP(c, 11); \
    LDP(c, 12); LDP(c, 13); LDP(c, 14); LDP(c, 15);
    DECLC(0) DECLC(1) DECLC(2) DECLC(3)
#undef DECLC
#undef LDP
#define PIN4(a, b_, c_, d_) asm volatile("" : "+v"(a), "+v"(b_), "+v"(c_), "+v"(d_))
#define PINC(c) \
    PIN4(w##c##_0,  w##c##_1,  w##c##_2,  w##c##_3);  \
    PIN4(w##c##_4,  w##c##_5,  w##c##_6,  w##c##_7);  \
    PIN4(w##c##_8,  w##c##_9,  w##c##_10, w##c##_11); \
    PIN4(w##c##_12, w##c##_13, w##c##_14, w##c##_15)
    PINC(0); PINC(1); PINC(2); PINC(3);
#undef PINC
#undef PIN4

    __shared__ __align__(16) float h_sh[2][4][36];
    __shared__ unsigned char mask_sh[T];

    if (tid < H) { h_sh[0][tid >> 5][tid & 31] = 0.f; }
    mask_sh[tid] = (x[(size_t)b * T + tid] != 0) ? 1 : 0;
    float c_reg = 0.f, h_reg = 0.f;
    __syncthreads();

    const int t0 = dir ? T - 1 : 0;
    const ptrdiff_t dstep = dir ? -(ptrdiff_t)G4 : (ptrdiff_t)G4;
    const ptrdiff_t hstep = dir ? -(ptrdiff_t)HOUT : (ptrdiff_t)HOUT;
    const float* xptr = xp + ((size_t)b * T + t0) * G4 + ks * H + q;
    float*       hptr = hout + ((size_t)b * T + t0) * HOUT + dir * H + q;
    float xp_cur = *xptr;

    int cb = 0;
    int t = t0;
    const int tinc = dir ? -1 : 1;

    for (int s = 0; s < T; s++) {
        float xin = xp_cur;
        if (s + 1 < T) {
            xptr += dstep;
            xp_cur = *xptr;
        }

        v2f acc0 = { (ks == 0) ? xin : 0.f, 0.f };
        v2f acc1 = { (ks == 1) ? xin : 0.f, 0.f };
        v2f acc2 = { (ks == 2) ? xin : 0.f, 0.f };
        v2f acc3 = { (ks == 3) ? xin : 0.f, 0.f };

        const v4f* hp = (const v4f*)&h_sh[cb][ks][0];
#define STEP4(kk, pA, pB) { \
        v4f hv = hp[kk]; \
        v2f h01 = __builtin_shufflevector(hv, hv, 0, 1); \
        v2f h23 = __builtin_shufflevector(hv, hv, 2, 3); \
        PKFMA(acc0, h01, w0_##pA); PKFMA(acc0, h23, w0_##pB); \
        PKFMA(acc1, h01, w1_##pA); PKFMA(acc1, h23, w1_##pB); \
        PKFMA(acc2, h01, w2_##pA); PKFMA(acc2, h23, w2_##pB); \
        PKFMA(acc3, h01, w3_##pA); PKFMA(acc3, h23, w3_##pB); }
        STEP4(0, 0, 1)   STEP4(1, 2, 3)   STEP4(2, 4, 5)   STEP4(3, 6, 7)
        STEP4(4, 8, 9)   STEP4(5, 10, 11) STEP4(6, 12, 13) STEP4(7, 14, 15)
#undef STEP4

        float a0 = acc0.x + acc0.y;
        float a1 = acc1.x + acc1.y;
        float a2 = acc2.x + acc2.y;
        float a3 = acc3.x + acc3.y;

        a0 = dpp_add<0xB1>(a0); a1 = dpp_add<0xB1>(a1);
        a2 = dpp_add<0xB1>(a2); a3 = dpp_add<0xB1>(a3);
        a0 = dpp_add<0x4E>(a0); a1 = dpp_add<0x4E>(a1);
        a2 = dpp_add<0x4E>(a2); a3 = dpp_add<0x4E>(a3);

        float ig = fast_sig(a0);
        float fg = fast_sig(a1);
        float gg = 2.f * fast_sig(a2 + a2) - 1.f;
        float og = fast_sig(a3);
        float cn = fmaf(fg, c_reg, ig * gg);
        float th = 2.f * fast_sig(cn + cn) - 1.f;
        float hn = og * th;

        bool msk = mask_sh[t] != 0;
        c_reg = msk ? cn : c_reg;
        h_reg = msk ? hn : h_reg;

        if (ks == 0) {
            h_sh[cb ^ 1][q >> 5][q & 31] = h_reg;
            *hptr = h_reg;
        }
        hptr += hstep;
        wg_barrier_lds();
        cb ^= 1;
        t += tinc;
    }
}

// ---------------------------------------------------------------------------
// 4) pooling: per (b,t) max & mean over 256 channels -> feat (B, 2T)
// ---------------------------------------------------------------------------
__global__ __launch_bounds__(256) void pool_kernel(
    const float* __restrict__ Hin, float* __restrict__ feat)
{
    int wave = threadIdx.x >> 6;
    int lane = threadIdx.x & 63;
    int bt = blockIdx.x * 4 + wave;
    float4 v = *(const float4*)&Hin[(size_t)bt * HOUT + lane * 4];
    float mx = fmaxf(fmaxf(v.x, v.y), fmaxf(v.z, v.w));
    float sm = (v.x + v.y) + (v.z + v.w);
#pragma unroll
    for (int off = 32; off > 0; off >>= 1) {
        mx = fmaxf(mx, __shfl_down(mx, off));
        sm += __shfl_down(sm, off);
    }
    if (lane == 0) {
        int b = bt >> 9;
        int t = bt & (T - 1);
        feat[(size_t)b * (2 * T) + t]     = mx;
        feat[(size_t)b * (2 * T) + T + t] = sm * (1.f / 256.f);
    }
}

// ---------------------------------------------------------------------------
// 5) FC: out(B,10) = relu(feat(B,1024) @ fcW(1024,10) + fcb)
// ---------------------------------------------------------------------------
__global__ __launch_bounds__(128) void fc_kernel(
    const float* __restrict__ feat, const float* __restrict__ fcW,
    const float* __restrict__ fcb, float* __restrict__ out)
{
    __shared__ float red[2][NUM_CLASSES];
    int b = blockIdx.x, tid = threadIdx.x;
    float acc[NUM_CLASSES];
#pragma unroll
    for (int c = 0; c < NUM_CLASSES; c++) acc[c] = 0.f;
#pragma unroll
    for (int it = 0; it < 8; it++) {
        int k = tid + it * 128;
        float fv = feat[(size_t)b * 1024 + k];
#pragma unroll
        for (int c = 0; c < NUM_CLASSES; c++)
            acc[c] = fmaf(fv, fcW[(size_t)k * NUM_CLASSES + c], acc[c]);
    }
#pragma unroll
    for (int c = 0; c < NUM_CLASSES; c++) {
        float v = acc[c];
        for (int off = 32; off > 0; off >>= 1) v += __shfl_down(v, off);
        if ((tid & 63) == 0) red[tid >> 6][c] = v;
    }
    __syncthreads();
    if (tid < NUM_CLASSES) {
        float v = red[0][tid] + red[1][tid] + fcb[tid];
        out[(size_t)b * NUM_CLASSES + tid] = fmaxf(v, 0.f);
    }
}

// ---------------------------------------------------------------------------
// launch
// ws layout (MiB): [0,32) H0 (later reused as H1) | [32,96) xpF |
// [96,160) xpB | [160,192) a2 | [192,193) w2t | [193,193.25) feat
// ---------------------------------------------------------------------------
extern "C" void kernel_launch(void* const* d_in, const int* in_sizes, int n_in,
                              void* d_out, int out_size, void* d_ws, size_t ws_size,
                              hipStream_t stream)
{
    const int*   x     = (const int*)d_in[0];
    const float* emb   = (const float*)d_in[1];
    const float* Wx_f0 = (const float*)d_in[2];
    const float* Wh_f0 = (const float*)d_in[3];
    const float* b_f0  = (const float*)d_in[4];
    const float* Wx_b0 = (const float*)d_in[5];
    const float* Wh_b0 = (const float*)d_in[6];
    const float* b_b0  = (const float*)d_in[7];
    const float* Wx_f1 = (const float*)d_in[8];
    const float* Wh_f1 = (const float*)d_in[9];
    const float* b_f1  = (const float*)d_in[10];
    const float* Wx_b1 = (const float*)d_in[11];
    const float* Wh_b1 = (const float*)d_in[12];
    const float* b_b1  = (const float*)d_in[13];
    const float* fcW   = (const float*)d_in[14];
    const float* fcb   = (const float*)d_in[15];
    float* out = (float*)d_out;

    char* ws = (char*)d_ws;
    const size_t MB = 1024 * 1024;
    float*          Hbuf = (float*)(ws);                   // H0, then H1
    float*          xpF  = (float*)(ws + 32 * MB);
    float*          xpB  = (float*)(ws + 96 * MB);
    unsigned short* a2   = (unsigned short*)(ws + 160 * MB);
    unsigned short* w2t  = (unsigned short*)(ws + 192 * MB);
    float*          feat = (float*)(ws + 193 * MB);

    dim3 ggrid(1024 / 128, BT / 128);  // (8, 256)

    // ---- layer 0 (K = 128) ----
    prep_w2t_kernel<<<1024, 128, 0, stream>>>(Wx_f0, Wx_b0, w2t, EMBED);
    prep_a2_emb_kernel<<<BT, 128, 0, stream>>>(x, emb, a2);
    gemm_mfma_kernel<<<ggrid, 256, 0, stream>>>(a2, w2t, b_f0, b_b0, xpF, xpB, EMBED);
    lstm_scan_kernel<<<dim3(B, 2), 512, 0, stream>>>(xpF, xpB, Wh_f0, Wh_b0, x, Hbuf);

    // ---- layer 1 (K = 256) ----
    prep_w2t_kernel<<<1024, 128, 0, stream>>>(Wx_f1, Wx_b1, w2t, 2 * H);
    prep_a2_h_kernel<<<BT, 256, 0, stream>>>(Hbuf, a2);
    gemm_mfma_kernel<<<ggrid, 256, 0, stream>>>(a2, w2t, b_f1, b_b1, xpF, xpB, 2 * H);
    lstm_scan_kernel<<<dim3(B, 2), 512, 0, stream>>>(xpF, xpB, Wh_f1, Wh_b1, x, Hbuf);

    // ---- pooling + FC ----
    pool_kernel<<<BT / 4, 256, 0, stream>>>(Hbuf, feat);
    fc_kernel<<<B, 128, 0, stream>>>(feat, fcW, fcb, out);
}